// Round 1
// baseline (4923.179 us; speedup 1.0000x reference)
//
#include <hip/hip_runtime.h>
#include <cstdint>
#include <cstddef>

// Problem constants
static constexpr int Bn  = 32;     // batch
static constexpr int Tn  = 32;     // decoder steps
static constexpr int Sn  = 100;    // encoder length
static constexpr int Vn  = 20000;  // vocab
static constexpr int SEn = 400;    // word emb
static constexpr int EINn= 460;    // SE + FR
static constexpr int Hn  = 512;    // decoder hidden
static constexpr int HHn = 256;    // per-direction encoder hidden
static constexpr int TEn = 300;    // target emb

__device__ __forceinline__ float sigm(float x) { return 1.f / (1.f + expf(-x)); }

// ---------------------------------------------------------------------------
// Embedding gathers: enc_in [B,S,460] = [sent_emb[value] | field | ppos | pneg]
//                    x_seq  [B,T,400] = sent_emb[sent]
// ---------------------------------------------------------------------------
__global__ __launch_bounds__(256) void embed_kernel(
    const int* __restrict__ value, const int* __restrict__ field,
    const int* __restrict__ ppos, const int* __restrict__ pneg,
    const int* __restrict__ sent,
    const float* __restrict__ sent_emb, const float* __restrict__ field_emb,
    const float* __restrict__ ppos_emb, const float* __restrict__ pneg_emb,
    float* __restrict__ enc_in, float* __restrict__ x_seq)
{
    int i = blockIdx.x * 256 + threadIdx.x;
    const int total1 = Bn * Sn * EINn;
    if (i < total1) {
        int e = i % EINn, bs = i / EINn;
        float v;
        if (e < SEn)      v = sent_emb[(size_t)value[bs] * SEn + e];
        else if (e < 450) v = field_emb[field[bs] * 50 + (e - 400)];
        else if (e < 455) v = ppos_emb[ppos[bs] * 5 + (e - 450)];
        else              v = pneg_emb[pneg[bs] * 5 + (e - 455)];
        enc_in[i] = v;
    } else {
        int i2 = i - total1;
        if (i2 < Bn * Tn * SEn) {
            int e = i2 % SEn, bt = i2 / SEn;
            x_seq[i2] = sent_emb[(size_t)sent[bt] * SEn + e];
        }
    }
}

// ---------------------------------------------------------------------------
// Generic fp32 tiled GEMM: C[M,N] = A[M,K] @ B[K,N] (+bias), 128x128 tile,
// 8x8 per thread, BK=8, bounds-checked everywhere.
// ---------------------------------------------------------------------------
__global__ __launch_bounds__(256) void gemm128_kernel(
    const float* __restrict__ A, const float* __restrict__ Bm,
    const float* __restrict__ bias, float* __restrict__ C,
    int M, int N, int K, int lda, int ldb, int ldc)
{
    __shared__ float As[8][128];
    __shared__ float Bs[8][128];
    const int bm = blockIdx.y * 128, bn = blockIdx.x * 128;
    const int tid = threadIdx.x;
    const int tx = tid & 15, ty = tid >> 4;
    const int row0 = ty * 8, col0 = tx * 8;
    float acc[8][8] = {};
    for (int k0 = 0; k0 < K; k0 += 8) {
        #pragma unroll
        for (int i = 0; i < 4; ++i) {
            int idx = tid + 256 * i;
            int m = idx >> 3, kk = idx & 7;
            float v = 0.f;
            if (bm + m < M && k0 + kk < K) v = A[(size_t)(bm + m) * lda + (k0 + kk)];
            As[kk][m] = v;
        }
        #pragma unroll
        for (int i = 0; i < 4; ++i) {
            int idx = tid + 256 * i;
            int kk = idx >> 7, n = idx & 127;
            float v = 0.f;
            if (k0 + kk < K && bn + n < N) v = Bm[(size_t)(k0 + kk) * ldb + (bn + n)];
            Bs[kk][n] = v;
        }
        __syncthreads();
        #pragma unroll
        for (int kk = 0; kk < 8; ++kk) {
            float a[8], b[8];
            #pragma unroll
            for (int i = 0; i < 8; ++i) a[i] = As[kk][row0 + i];
            #pragma unroll
            for (int j = 0; j < 8; ++j) b[j] = Bs[kk][col0 + j];
            #pragma unroll
            for (int i = 0; i < 8; ++i)
                #pragma unroll
                for (int j = 0; j < 8; ++j) acc[i][j] = fmaf(a[i], b[j], acc[i][j]);
        }
        __syncthreads();
    }
    #pragma unroll
    for (int i = 0; i < 8; ++i) {
        int m = bm + row0 + i;
        if (m >= M) continue;
        #pragma unroll
        for (int j = 0; j < 8; ++j) {
            int n = bn + col0 + j;
            if (n < N) {
                float v = acc[i][j];
                if (bias) v += bias[n];
                C[(size_t)m * ldc + n] = v;
            }
        }
    }
}

// ---------------------------------------------------------------------------
// Encoder bidirectional LSTM. One block per (batch, dir). 1024 threads:
// thread u computes gate unit u (z = Xpre + h@Wh). Threads <256 update c,h.
// Gate order (torch): i | f | g | o, 256 each.
// ---------------------------------------------------------------------------
__global__ __launch_bounds__(1024) void enc_lstm_kernel(
    const float* __restrict__ Xf, const float* __restrict__ Xb,
    const float* __restrict__ Whf, const float* __restrict__ Whb,
    float* __restrict__ enc_out, float* __restrict__ h0, float* __restrict__ c0)
{
    const int b = blockIdx.x >> 1, dir = blockIdx.x & 1;
    const float* __restrict__ X  = dir ? Xb : Xf;
    const float* __restrict__ Wh = dir ? Whb : Whf;
    __shared__ float h_sh[HHn];
    __shared__ float z_sh[4 * HHn];
    const int u = threadIdx.x;
    float c = 0.f;
    if (u < HHn) h_sh[u] = 0.f;
    __syncthreads();
    for (int step = 0; step < Sn; ++step) {
        const int s = dir ? (Sn - 1 - step) : step;
        const float* xrow = X + ((size_t)b * Sn + s) * 1024;
        float z = xrow[u];
        #pragma unroll 4
        for (int k = 0; k < HHn; ++k)
            z = fmaf(h_sh[k], Wh[k * 1024 + u], z);
        z_sh[u] = z;
        __syncthreads();
        if (u < HHn) {
            float zi = z_sh[u], zf = z_sh[HHn + u], zg = z_sh[2 * HHn + u], zo = z_sh[3 * HHn + u];
            c = sigm(zf) * c + sigm(zi) * tanhf(zg);
            float h = sigm(zo) * tanhf(c);
            h_sh[u] = h;
            enc_out[((size_t)b * Sn + s) * Hn + dir * HHn + u] = h;
            if (step == Sn - 1) {
                h0[b * Hn + dir * HHn + u] = h;
                c0[b * Hn + dir * HHn + u] = c;
            }
        }
        __syncthreads();
    }
}

// ---------------------------------------------------------------------------
// Decoder LSTM. One block per batch, 1024 threads: thread u computes gate
// units u and 1024+u. Threads <512 update c,h. Gates i|f|g|o, 512 each.
// ---------------------------------------------------------------------------
__global__ __launch_bounds__(1024) void dec_lstm_kernel(
    const float* __restrict__ Xd, const float* __restrict__ Whd,
    const float* __restrict__ h0, const float* __restrict__ c0,
    float* __restrict__ h_all, float* __restrict__ hT, float* __restrict__ cT)
{
    const int b = blockIdx.x;
    __shared__ float h_sh[Hn];
    __shared__ float z_sh[4 * Hn];
    const int u = threadIdx.x;
    float c = 0.f;
    if (u < Hn) { h_sh[u] = h0[b * Hn + u]; c = c0[b * Hn + u]; }
    __syncthreads();
    for (int t = 0; t < Tn; ++t) {
        const float* xrow = Xd + ((size_t)b * Tn + t) * 2048;
        float z0 = xrow[u], z1 = xrow[1024 + u];
        #pragma unroll 4
        for (int k = 0; k < Hn; ++k) {
            float hk = h_sh[k];
            z0 = fmaf(hk, Whd[(size_t)k * 2048 + u], z0);
            z1 = fmaf(hk, Whd[(size_t)k * 2048 + 1024 + u], z1);
        }
        z_sh[u] = z0; z_sh[1024 + u] = z1;
        __syncthreads();
        if (u < Hn) {
            float zi = z_sh[u], zf = z_sh[Hn + u], zg = z_sh[2 * Hn + u], zo = z_sh[3 * Hn + u];
            c = sigm(zf) * c + sigm(zi) * tanhf(zg);
            float h = sigm(zo) * tanhf(c);
            h_sh[u] = h;
            h_all[((size_t)b * Tn + t) * Hn + u] = h;
            if (t == Tn - 1) { hT[b * Hn + u] = h; cT[b * Hn + u] = c; }
        }
        __syncthreads();
    }
}

// ---------------------------------------------------------------------------
// Post-recurrence decoder step (fully parallel over (b,t)):
// dual attention, ctx, out=tanh([h;ctx]Wo), lam, attn argmax -> attn_pred.
// ---------------------------------------------------------------------------
__global__ __launch_bounds__(256) void dec_post_kernel(
    const float* __restrict__ h_all, const float* __restrict__ enc_proj,
    const float* __restrict__ z_proj, const float* __restrict__ enc_out,
    const float* __restrict__ x_seq, const float* __restrict__ Wo,
    const float* __restrict__ Wl, const float* __restrict__ bl,
    const int* __restrict__ value, const float* __restrict__ target_emb,
    float* __restrict__ outs, float* __restrict__ gattn,
    float* __restrict__ lamv, float* __restrict__ attn_pred)
{
    const int bt = blockIdx.x, b = bt >> 5;  // T=32
    const int tid = threadIdx.x;
    __shared__ float h_sh[Hn];
    __shared__ float sc[2 * Sn];
    __shared__ float g_sh[Sn];
    __shared__ float ctx_sh[Hn];
    __shared__ float red[256];
    __shared__ int smax_sh;

    for (int i = tid; i < Hn; i += 256) h_sh[i] = h_all[(size_t)bt * Hn + i];
    __syncthreads();

    const int wave = tid >> 6, lane = tid & 63;
    for (int s = wave; s < Sn; s += 4) {
        const float* ep = enc_proj + ((size_t)b * Sn + s) * Hn;
        const float* zp = z_proj  + ((size_t)b * Sn + s) * Hn;
        float da = 0.f, db = 0.f;
        for (int j = lane; j < Hn; j += 64) {
            float hv = h_sh[j];
            da = fmaf(ep[j], hv, da);
            db = fmaf(zp[j], hv, db);
        }
        #pragma unroll
        for (int off = 32; off; off >>= 1) {
            da += __shfl_down(da, off);
            db += __shfl_down(db, off);
        }
        if (lane == 0) { sc[s] = da; sc[Sn + s] = db; }
    }
    __syncthreads();

    if (tid == 0) {
        float ma = -1e30f, mb = -1e30f;
        for (int s = 0; s < Sn; ++s) { ma = fmaxf(ma, sc[s]); mb = fmaxf(mb, sc[Sn + s]); }
        float sa = 0.f, sb = 0.f;
        for (int s = 0; s < Sn; ++s) {
            float ea = expf(sc[s] - ma), eb = expf(sc[Sn + s] - mb);
            sc[s] = ea; sc[Sn + s] = eb; sa += ea; sb += eb;
        }
        float gs = 0.f;
        for (int s = 0; s < Sn; ++s) { float g = (sc[s] / sa) * (sc[Sn + s] / sb); g_sh[s] = g; gs += g; }
        float inv = 1.f / (gs + 1e-9f);
        float best = -1.f; int bi = 0;
        for (int s = 0; s < Sn; ++s) {
            float g = g_sh[s] * inv; g_sh[s] = g;
            if (g > best) { best = g; bi = s; }  // strict > keeps first index (np.argmax)
        }
        smax_sh = bi;
    }
    __syncthreads();

    for (int s = tid; s < Sn; s += 256) gattn[(size_t)bt * Sn + s] = g_sh[s];
    const int word = value[b * Sn + smax_sh];
    for (int e = tid; e < TEn; e += 256)
        attn_pred[(size_t)bt * TEn + e] = target_emb[(size_t)word * TEn + e];

    for (int u = tid; u < Hn; u += 256) {
        float acc = 0.f;
        for (int s = 0; s < Sn; ++s)
            acc = fmaf(g_sh[s], enc_out[((size_t)b * Sn + s) * Hn + u], acc);
        ctx_sh[u] = acc;
    }
    __syncthreads();

    for (int j = tid; j < Hn; j += 256) {
        float acc = 0.f;
        for (int k = 0; k < Hn; ++k) acc = fmaf(h_sh[k], Wo[(size_t)k * Hn + j], acc);
        for (int k = 0; k < Hn; ++k) acc = fmaf(ctx_sh[k], Wo[(size_t)(Hn + k) * Hn + j], acc);
        outs[(size_t)bt * Hn + j] = tanhf(acc);
    }

    float part = 0.f;
    for (int k = tid; k < Hn; k += 256) part = fmaf(h_sh[k], Wl[k], part);
    for (int k = tid; k < Hn; k += 256) part = fmaf(ctx_sh[k], Wl[Hn + k], part);
    const float* xr = x_seq + (size_t)bt * SEn;
    for (int k = tid; k < SEn; k += 256) part = fmaf(xr[k], Wl[2 * Hn + k], part);
    red[tid] = part;
    __syncthreads();
    for (int s2 = 128; s2; s2 >>= 1) {
        if (tid < s2) red[tid] += red[tid + s2];
        __syncthreads();
    }
    if (tid == 0) lamv[bt] = 1.f / (1.f + expf(-(red[0] + bl[0])));
}

// ---------------------------------------------------------------------------
// p_lex[b,t,:] = sum_s g[b,t,s] * align_prob[b,s,:]
// Block = (b, t-half of 16, v-chunk of 1024). Each align_prob elem read once.
// ---------------------------------------------------------------------------
__global__ __launch_bounds__(256) void p_lex_kernel(
    const float* __restrict__ gattn, const float* __restrict__ align_prob,
    float* __restrict__ p_lex)
{
    const int b = blockIdx.z, th = blockIdx.y, vc = blockIdx.x;
    const int tid = threadIdx.x;
    __shared__ float gT[Sn][17];
    for (int i = tid; i < Sn * 16; i += 256) {
        int s = i >> 4, tt = i & 15;
        gT[s][tt] = gattn[((size_t)(b * Tn + th * 16 + tt)) * Sn + s];
    }
    __syncthreads();
    const int v0 = vc * 1024 + tid * 4;
    if (v0 >= Vn) return;  // V=20000: tail chunk has 544 valid (mult of 4)
    float acc[16][4] = {};
    for (int s = 0; s < Sn; ++s) {
        const float4 a = *(const float4*)(align_prob + ((size_t)b * Sn + s) * Vn + v0);
        #pragma unroll
        for (int tt = 0; tt < 16; ++tt) {
            float g = gT[s][tt];
            acc[tt][0] = fmaf(g, a.x, acc[tt][0]);
            acc[tt][1] = fmaf(g, a.y, acc[tt][1]);
            acc[tt][2] = fmaf(g, a.z, acc[tt][2]);
            acc[tt][3] = fmaf(g, a.w, acc[tt][3]);
        }
    }
    #pragma unroll
    for (int tt = 0; tt < 16; ++tt) {
        float4 o;
        o.x = acc[tt][0]; o.y = acc[tt][1]; o.z = acc[tt][2]; o.w = acc[tt][3];
        *(float4*)(p_lex + ((size_t)(b * Tn + th * 16 + tt)) * Vn + v0) = o;
    }
}

// ---------------------------------------------------------------------------
// Row reductions for the double log_softmax. One block per (b,t) row.
// ---------------------------------------------------------------------------
__global__ __launch_bounds__(256) void reduce1_kernel(
    const float* __restrict__ z, float* __restrict__ lse1)
{
    const int r = blockIdx.x, tid = threadIdx.x;
    const float* row = z + (size_t)r * Vn;
    __shared__ float red[256];
    float m = -1e30f;
    for (int v = tid; v < Vn; v += 256) m = fmaxf(m, row[v]);
    red[tid] = m; __syncthreads();
    for (int s = 128; s; s >>= 1) { if (tid < s) red[tid] = fmaxf(red[tid], red[tid + s]); __syncthreads(); }
    m = red[0]; __syncthreads();
    float sum = 0.f;
    for (int v = tid; v < Vn; v += 256) sum += expf(row[v] - m);
    red[tid] = sum; __syncthreads();
    for (int s = 128; s; s >>= 1) { if (tid < s) red[tid] += red[tid + s]; __syncthreads(); }
    if (tid == 0) lse1[r] = m + logf(red[0]);
}

__global__ __launch_bounds__(256) void combine_kernel(
    float* __restrict__ q, const float* __restrict__ p_lex,
    const float* __restrict__ lamv, const float* __restrict__ lse1,
    float* __restrict__ lse2, int* __restrict__ amax)
{
    const int r = blockIdx.x, tid = threadIdx.x;
    const float l = lamv[r], ls1 = lse1[r];
    float* row = q + (size_t)r * Vn;
    const float* pl = p_lex + (size_t)r * Vn;
    __shared__ float rm[256];
    __shared__ int ri[256];
    float m = -1e30f; int mi = 0;
    for (int v = tid; v < Vn; v += 256) {
        float qq = l * pl[v] + (1.f - l) * (row[v] - ls1);
        row[v] = qq;
        if (qq > m) { m = qq; mi = v; }  // strict > keeps smallest local index
    }
    rm[tid] = m; ri[tid] = mi; __syncthreads();
    for (int s = 128; s; s >>= 1) {
        if (tid < s) {
            if (rm[tid + s] > rm[tid] || (rm[tid + s] == rm[tid] && ri[tid + s] < ri[tid])) {
                rm[tid] = rm[tid + s]; ri[tid] = ri[tid + s];
            }
        }
        __syncthreads();
    }
    m = rm[0];
    const int best = ri[0];
    __syncthreads();
    float sum = 0.f;
    for (int v = tid; v < Vn; v += 256) sum += expf(row[v] - m);
    rm[tid] = sum; __syncthreads();
    for (int s = 128; s; s >>= 1) { if (tid < s) rm[tid] += rm[tid + s]; __syncthreads(); }
    if (tid == 0) { lse2[r] = m + logf(rm[0]); amax[r] = best; }
}

__global__ __launch_bounds__(256) void finalize_kernel(
    float* __restrict__ pbias, const float* __restrict__ lse2,
    const int* __restrict__ amax, const float* __restrict__ target_emb,
    float* __restrict__ dec_pred)
{
    const int r = blockIdx.x, tid = threadIdx.x;
    const float ls = lse2[r];
    float* row = pbias + (size_t)r * Vn;
    for (int v = tid; v < Vn; v += 256) row[v] -= ls;
    const int wd = amax[r];
    for (int e = tid; e < TEn; e += 256)
        dec_pred[(size_t)r * TEn + e] = target_emb[(size_t)wd * TEn + e];
}

// ---------------------------------------------------------------------------
extern "C" void kernel_launch(void* const* d_in, const int* in_sizes, int n_in,
                              void* d_out, int out_size, void* d_ws, size_t ws_size,
                              hipStream_t stream)
{
    const int*   sent       = (const int*)d_in[0];
    const int*   value      = (const int*)d_in[1];
    const int*   field      = (const int*)d_in[2];
    const int*   ppos       = (const int*)d_in[3];
    const int*   pneg       = (const int*)d_in[4];
    // d_in[5] = batch_size (unused), d_in[6] = value_mask (unused by reference)
    const float* align_prob = (const float*)d_in[7];
    const float* sent_emb   = (const float*)d_in[8];
    const float* field_emb  = (const float*)d_in[9];
    const float* ppos_emb   = (const float*)d_in[10];
    const float* pneg_emb   = (const float*)d_in[11];
    const float* target_emb = (const float*)d_in[12];
    const float* Wi_f = (const float*)d_in[13];
    const float* Wh_f = (const float*)d_in[14];
    const float* b_f  = (const float*)d_in[15];
    const float* Wi_b = (const float*)d_in[16];
    const float* Wh_b = (const float*)d_in[17];
    const float* b_b  = (const float*)d_in[18];
    const float* Wi_d = (const float*)d_in[19];
    const float* Wh_d = (const float*)d_in[20];
    const float* b_d  = (const float*)d_in[21];
    const float* Wa   = (const float*)d_in[22];
    const float* Wf   = (const float*)d_in[23];
    const float* Wo   = (const float*)d_in[24];
    const float* Wl   = (const float*)d_in[25];
    const float* bl   = (const float*)d_in[26];
    const float* Wout = (const float*)d_in[27];
    const float* bout = (const float*)d_in[28];

    // Workspace layout (floats). Total ~37.1M floats = ~148.5 MB.
    float* w = (float*)d_ws;
    float* enc_in   = w; w += (size_t)Bn * Sn * EINn;   // 1,472,000
    float* x_seq    = w; w += (size_t)Bn * Tn * SEn;    //   409,600
    float* Xf       = w; w += (size_t)Bn * Sn * 1024;   // 3,276,800
    float* Xb       = w; w += (size_t)Bn * Sn * 1024;   // 3,276,800
    float* Xd       = w; w += (size_t)Bn * Tn * 2048;   // 2,097,152
    float* enc_out  = w; w += (size_t)Bn * Sn * Hn;     // 1,638,400
    float* enc_proj = w; w += (size_t)Bn * Sn * Hn;     // 1,638,400
    float* z_proj   = w; w += (size_t)Bn * Sn * Hn;     // 1,638,400
    float* h0       = w; w += (size_t)Bn * Hn;          //    16,384
    float* c0       = w; w += (size_t)Bn * Hn;          //    16,384
    float* h_all    = w; w += (size_t)Bn * Tn * Hn;     //   524,288
    float* outs     = w; w += (size_t)Bn * Tn * Hn;     //   524,288
    float* gattn    = w; w += (size_t)Bn * Tn * Sn;     //   102,400
    float* lamv     = w; w += (size_t)Bn * Tn;          //     1,024
    float* p_lex    = w; w += (size_t)Bn * Tn * Vn;     // 20,480,000
    float* lse1     = w; w += (size_t)Bn * Tn;
    float* lse2     = w; w += (size_t)Bn * Tn;
    int*   amax     = (int*)w;

    float* outp      = (float*)d_out;
    float* pbias     = outp;                       // [B,T,V] 20,480,000
    float* hT        = outp + (size_t)20480000;    // [B,H]
    float* cT        = hT + Bn * Hn;               // [B,H]
    float* attn_pred = cT + Bn * Hn;               // [B,T,300]
    float* dec_pred  = attn_pred + (size_t)Bn * Tn * TEn;

    // 1. embeddings
    embed_kernel<<<7350, 256, 0, stream>>>(value, field, ppos, pneg, sent,
        sent_emb, field_emb, ppos_emb, pneg_emb, enc_in, x_seq);

    // 2. input-side GEMMs (hoisted out of the recurrences)
    dim3 gXf(8, 25);
    gemm128_kernel<<<gXf, 256, 0, stream>>>(enc_in, Wi_f, b_f, Xf, 3200, 1024, 460, 460, 1024, 1024);
    gemm128_kernel<<<gXf, 256, 0, stream>>>(enc_in, Wi_b, b_b, Xb, 3200, 1024, 460, 460, 1024, 1024);
    dim3 gXd(16, 8);
    gemm128_kernel<<<gXd, 256, 0, stream>>>(x_seq, Wi_d, b_d, Xd, 1024, 2048, 400, 400, 2048, 2048);

    // 3. encoder bidirectional LSTM (sequential over S)
    enc_lstm_kernel<<<64, 1024, 0, stream>>>(Xf, Xb, Wh_f, Wh_b, enc_out, h0, c0);

    // 4. attention key projections
    dim3 gPr(4, 25);
    gemm128_kernel<<<gPr, 256, 0, stream>>>(enc_out, Wa, nullptr, enc_proj, 3200, 512, 512, 512, 512, 512);
    gemm128_kernel<<<gPr, 256, 0, stream>>>(enc_in + 400, Wf, nullptr, z_proj, 3200, 512, 60, 460, 512, 512);

    // 5. decoder LSTM (sequential over T); writes hT/cT directly to d_out
    dec_lstm_kernel<<<32, 1024, 0, stream>>>(Xd, Wh_d, h0, c0, h_all, hT, cT);

    // 6. per-(b,t) attention/ctx/out/lam + attn argmax -> attn_pred
    dec_post_kernel<<<1024, 256, 0, stream>>>(h_all, enc_proj, z_proj, enc_out, x_seq,
        Wo, Wl, bl, value, target_emb, outs, gattn, lamv, attn_pred);

    // 7. zmod = outs @ Wout + bout  (written into d_out p_bias region)
    dim3 gBig(157, 8);
    gemm128_kernel<<<gBig, 256, 0, stream>>>(outs, Wout, bout, pbias, 1024, 20000, 512, 512, 20000, 20000);

    // 8. p_lex = attn @ align_prob
    dim3 gPl(20, 2, 32);
    p_lex_kernel<<<gPl, 256, 0, stream>>>(gattn, align_prob, p_lex);

    // 9-11. double log_softmax + argmax + gathers
    reduce1_kernel<<<1024, 256, 0, stream>>>(pbias, lse1);
    combine_kernel<<<1024, 256, 0, stream>>>(pbias, p_lex, lamv, lse1, lse2, amax);
    finalize_kernel<<<1024, 256, 0, stream>>>(pbias, lse2, amax, target_emb, dec_pred);

    (void)in_sizes; (void)n_in; (void)out_size; (void)ws_size;
}

// Round 2
// 4200.278 us; speedup vs baseline: 1.1721x; 1.1721x over previous
//
#include <hip/hip_runtime.h>
#include <cstdint>
#include <cstddef>

// Problem constants
static constexpr int Bn  = 32;     // batch
static constexpr int Tn  = 32;     // decoder steps
static constexpr int Sn  = 100;    // encoder length
static constexpr int Vn  = 20000;  // vocab
static constexpr int SEn = 400;    // word emb
static constexpr int EINn= 460;    // SE + FR
static constexpr int Hn  = 512;    // decoder hidden
static constexpr int HHn = 256;    // per-direction encoder hidden
static constexpr int TEn = 300;    // target emb

__device__ __forceinline__ float sigm(float x) { return 1.f / (1.f + expf(-x)); }

__device__ __forceinline__ void fma4(float hk, const float4 w,
                                     float& zi, float& zf, float& zg, float& zo) {
    zi = fmaf(hk, w.x, zi); zf = fmaf(hk, w.y, zf);
    zg = fmaf(hk, w.z, zg); zo = fmaf(hk, w.w, zo);
}

// ---------------------------------------------------------------------------
// Embedding gathers
// ---------------------------------------------------------------------------
__global__ __launch_bounds__(256) void embed_kernel(
    const int* __restrict__ value, const int* __restrict__ field,
    const int* __restrict__ ppos, const int* __restrict__ pneg,
    const int* __restrict__ sent,
    const float* __restrict__ sent_emb, const float* __restrict__ field_emb,
    const float* __restrict__ ppos_emb, const float* __restrict__ pneg_emb,
    float* __restrict__ enc_in, float* __restrict__ x_seq)
{
    int i = blockIdx.x * 256 + threadIdx.x;
    const int total1 = Bn * Sn * EINn;
    if (i < total1) {
        int e = i % EINn, bs = i / EINn;
        float v;
        if (e < SEn)      v = sent_emb[(size_t)value[bs] * SEn + e];
        else if (e < 450) v = field_emb[field[bs] * 50 + (e - 400)];
        else if (e < 455) v = ppos_emb[ppos[bs] * 5 + (e - 450)];
        else              v = pneg_emb[pneg[bs] * 5 + (e - 455)];
        enc_in[i] = v;
    } else {
        int i2 = i - total1;
        if (i2 < Bn * Tn * SEn) {
            int e = i2 % SEn, bt = i2 / SEn;
            x_seq[i2] = sent_emb[(size_t)sent[bt] * SEn + e];
        }
    }
}

// ---------------------------------------------------------------------------
// Weight transposes into [k][u][gate] float4 layout for the LSTM kernels.
// enc: Wh[k][g*256+u] -> Wt[(k*256+u)*4+g], k,u in [0,256)
// dec: Wh[k][g*512+u] -> Wt[(k*512+u)*4+g], k,u in [0,512)
// ---------------------------------------------------------------------------
__global__ __launch_bounds__(256) void transpose_wh_kernel(
    const float* __restrict__ Whf, const float* __restrict__ Whb,
    const float* __restrict__ Whd,
    float* __restrict__ Whf_t, float* __restrict__ Whb_t, float* __restrict__ Whd_t)
{
    int i = blockIdx.x * 256 + threadIdx.x;
    if (i < 65536) {  // 256*256
        int k = i >> 8, u = i & 255;
        const float* p = Whf + (size_t)k * 1024 + u;
        float4 o;
        o.x = p[0]; o.y = p[256]; o.z = p[512]; o.w = p[768];
        *(float4*)(Whf_t + (size_t)i * 4) = o;
        p = Whb + (size_t)k * 1024 + u;
        o.x = p[0]; o.y = p[256]; o.z = p[512]; o.w = p[768];
        *(float4*)(Whb_t + (size_t)i * 4) = o;
    } else {
        int j = i - 65536;  // 512*512 entries
        if (j < 262144) {
            int k = j >> 9, u = j & 511;
            const float* p = Whd + (size_t)k * 2048 + u;
            float4 o;
            o.x = p[0]; o.y = p[512]; o.z = p[1024]; o.w = p[1536];
            *(float4*)(Whd_t + (size_t)j * 4) = o;
        }
    }
}

// ---------------------------------------------------------------------------
// Generic fp32 tiled GEMM (unchanged from round 0)
// ---------------------------------------------------------------------------
__global__ __launch_bounds__(256) void gemm128_kernel(
    const float* __restrict__ A, const float* __restrict__ Bm,
    const float* __restrict__ bias, float* __restrict__ C,
    int M, int N, int K, int lda, int ldb, int ldc)
{
    __shared__ float As[8][128];
    __shared__ float Bs[8][128];
    const int bm = blockIdx.y * 128, bn = blockIdx.x * 128;
    const int tid = threadIdx.x;
    const int tx = tid & 15, ty = tid >> 4;
    const int row0 = ty * 8, col0 = tx * 8;
    float acc[8][8] = {};
    for (int k0 = 0; k0 < K; k0 += 8) {
        #pragma unroll
        for (int i = 0; i < 4; ++i) {
            int idx = tid + 256 * i;
            int m = idx >> 3, kk = idx & 7;
            float v = 0.f;
            if (bm + m < M && k0 + kk < K) v = A[(size_t)(bm + m) * lda + (k0 + kk)];
            As[kk][m] = v;
        }
        #pragma unroll
        for (int i = 0; i < 4; ++i) {
            int idx = tid + 256 * i;
            int kk = idx >> 7, n = idx & 127;
            float v = 0.f;
            if (k0 + kk < K && bn + n < N) v = Bm[(size_t)(k0 + kk) * ldb + (bn + n)];
            Bs[kk][n] = v;
        }
        __syncthreads();
        #pragma unroll
        for (int kk = 0; kk < 8; ++kk) {
            float a[8], b[8];
            #pragma unroll
            for (int i = 0; i < 8; ++i) a[i] = As[kk][row0 + i];
            #pragma unroll
            for (int j = 0; j < 8; ++j) b[j] = Bs[kk][col0 + j];
            #pragma unroll
            for (int i = 0; i < 8; ++i)
                #pragma unroll
                for (int j = 0; j < 8; ++j) acc[i][j] = fmaf(a[i], b[j], acc[i][j]);
        }
        __syncthreads();
    }
    #pragma unroll
    for (int i = 0; i < 8; ++i) {
        int m = bm + row0 + i;
        if (m >= M) continue;
        #pragma unroll
        for (int j = 0; j < 8; ++j) {
            int n = bn + col0 + j;
            if (n < N) {
                float v = acc[i][j];
                if (bias) v += bias[n];
                C[(size_t)m * ldc + n] = v;
            }
        }
    }
}

// ---------------------------------------------------------------------------
// Encoder bidir LSTM v2. Block = (batch, dir), 256 threads = 256 hidden units.
// Thread u computes all 4 gate dots via float4 weight loads -> c,h local.
// ---------------------------------------------------------------------------
__global__ __launch_bounds__(256) void enc_lstm2_kernel(
    const float* __restrict__ Xf, const float* __restrict__ Xb,
    const float4* __restrict__ Whf_t, const float4* __restrict__ Whb_t,
    float* __restrict__ enc_out, float* __restrict__ h0, float* __restrict__ c0)
{
    const int b = blockIdx.x >> 1, dir = blockIdx.x & 1;
    const float* __restrict__ X = dir ? Xb : Xf;
    const float4* __restrict__ W = dir ? Whb_t : Whf_t;
    __shared__ __align__(16) float h_sh[HHn];
    const int u = threadIdx.x;
    float c = 0.f;
    h_sh[u] = 0.f;
    __syncthreads();
    for (int step = 0; step < Sn; ++step) {
        const int s = dir ? (Sn - 1 - step) : step;
        const float* xr = X + ((size_t)(b * Sn + s)) * 1024;
        float zi = xr[u], zf = xr[256 + u], zg = xr[512 + u], zo = xr[768 + u];
        #pragma unroll 4
        for (int k4 = 0; k4 < 64; ++k4) {
            const float4 hv = *(const float4*)&h_sh[k4 << 2];
            const float4 w0 = W[((k4 << 2) + 0) * 256 + u];
            const float4 w1 = W[((k4 << 2) + 1) * 256 + u];
            const float4 w2 = W[((k4 << 2) + 2) * 256 + u];
            const float4 w3 = W[((k4 << 2) + 3) * 256 + u];
            fma4(hv.x, w0, zi, zf, zg, zo);
            fma4(hv.y, w1, zi, zf, zg, zo);
            fma4(hv.z, w2, zi, zf, zg, zo);
            fma4(hv.w, w3, zi, zf, zg, zo);
        }
        c = sigm(zf) * c + sigm(zi) * tanhf(zg);
        float h = sigm(zo) * tanhf(c);
        __syncthreads();
        h_sh[u] = h;
        enc_out[((size_t)(b * Sn + s)) * Hn + dir * HHn + u] = h;
        if (step == Sn - 1) {
            h0[b * Hn + dir * HHn + u] = h;
            c0[b * Hn + dir * HHn + u] = c;
        }
        __syncthreads();
    }
}

// ---------------------------------------------------------------------------
// Decoder LSTM v2 — cooperative. 64 blocks x 256 threads; block j handles
// batch j>>1, units [(j&1)*256, +256). h exchanged via agent-scope hbuf with
// a monotonic atomic-counter grid barrier (one per step).
// ---------------------------------------------------------------------------
__global__ __launch_bounds__(256) void dec_lstm2_kernel(
    const float* __restrict__ Xd, const float4* __restrict__ Whd_t,
    const float* __restrict__ h0, const float* __restrict__ c0,
    float* __restrict__ h_all, float* __restrict__ hT, float* __restrict__ cT,
    float* __restrict__ hbuf, int* __restrict__ bar)
{
    const int b = blockIdx.x >> 1;
    const int tid = threadIdx.x;
    const int u = ((blockIdx.x & 1) << 8) + tid;
    __shared__ __align__(16) float h_sh[Hn];
    h_sh[tid]       = h0[b * Hn + tid];
    h_sh[tid + 256] = h0[b * Hn + 256 + tid];
    float c = c0[b * Hn + u];
    __syncthreads();
    for (int t = 0; t < Tn; ++t) {
        const float* xr = Xd + ((size_t)(b * Tn + t)) * 2048;
        float zi = xr[u], zf = xr[512 + u], zg = xr[1024 + u], zo = xr[1536 + u];
        #pragma unroll 4
        for (int k4 = 0; k4 < 128; ++k4) {
            const float4 hv = *(const float4*)&h_sh[k4 << 2];
            const float4 w0 = Whd_t[((k4 << 2) + 0) * 512 + u];
            const float4 w1 = Whd_t[((k4 << 2) + 1) * 512 + u];
            const float4 w2 = Whd_t[((k4 << 2) + 2) * 512 + u];
            const float4 w3 = Whd_t[((k4 << 2) + 3) * 512 + u];
            fma4(hv.x, w0, zi, zf, zg, zo);
            fma4(hv.y, w1, zi, zf, zg, zo);
            fma4(hv.z, w2, zi, zf, zg, zo);
            fma4(hv.w, w3, zi, zf, zg, zo);
        }
        c = sigm(zf) * c + sigm(zi) * tanhf(zg);
        float h = sigm(zo) * tanhf(c);
        h_all[((size_t)(b * Tn + t)) * Hn + u] = h;
        if (t == Tn - 1) { hT[b * Hn + u] = h; cT[b * Hn + u] = c; }
        __hip_atomic_store(&hbuf[b * Hn + u], h, __ATOMIC_RELEASE, __HIP_MEMORY_SCOPE_AGENT);
        __syncthreads();
        if (t == Tn - 1) break;
        if (tid == 0) {
            __hip_atomic_fetch_add(bar, 1, __ATOMIC_ACQ_REL, __HIP_MEMORY_SCOPE_AGENT);
            const int target = 64 * (t + 1);
            while (__hip_atomic_load(bar, __ATOMIC_ACQUIRE, __HIP_MEMORY_SCOPE_AGENT) < target)
                __builtin_amdgcn_s_sleep(8);
        }
        __syncthreads();
        h_sh[tid]       = __hip_atomic_load(&hbuf[b * Hn + tid],       __ATOMIC_ACQUIRE, __HIP_MEMORY_SCOPE_AGENT);
        h_sh[tid + 256] = __hip_atomic_load(&hbuf[b * Hn + 256 + tid], __ATOMIC_ACQUIRE, __HIP_MEMORY_SCOPE_AGENT);
        __syncthreads();
    }
}

// ---------------------------------------------------------------------------
// Post-recurrence decoder step (unchanged)
// ---------------------------------------------------------------------------
__global__ __launch_bounds__(256) void dec_post_kernel(
    const float* __restrict__ h_all, const float* __restrict__ enc_proj,
    const float* __restrict__ z_proj, const float* __restrict__ enc_out,
    const float* __restrict__ x_seq, const float* __restrict__ Wo,
    const float* __restrict__ Wl, const float* __restrict__ bl,
    const int* __restrict__ value, const float* __restrict__ target_emb,
    float* __restrict__ outs, float* __restrict__ gattn,
    float* __restrict__ lamv, float* __restrict__ attn_pred)
{
    const int bt = blockIdx.x, b = bt >> 5;
    const int tid = threadIdx.x;
    __shared__ float h_sh[Hn];
    __shared__ float sc[2 * Sn];
    __shared__ float g_sh[Sn];
    __shared__ float ctx_sh[Hn];
    __shared__ float red[256];
    __shared__ int smax_sh;

    for (int i = tid; i < Hn; i += 256) h_sh[i] = h_all[(size_t)bt * Hn + i];
    __syncthreads();

    const int wave = tid >> 6, lane = tid & 63;
    for (int s = wave; s < Sn; s += 4) {
        const float* ep = enc_proj + ((size_t)b * Sn + s) * Hn;
        const float* zp = z_proj  + ((size_t)b * Sn + s) * Hn;
        float da = 0.f, db = 0.f;
        for (int j = lane; j < Hn; j += 64) {
            float hv = h_sh[j];
            da = fmaf(ep[j], hv, da);
            db = fmaf(zp[j], hv, db);
        }
        #pragma unroll
        for (int off = 32; off; off >>= 1) {
            da += __shfl_down(da, off);
            db += __shfl_down(db, off);
        }
        if (lane == 0) { sc[s] = da; sc[Sn + s] = db; }
    }
    __syncthreads();

    if (tid == 0) {
        float ma = -1e30f, mb = -1e30f;
        for (int s = 0; s < Sn; ++s) { ma = fmaxf(ma, sc[s]); mb = fmaxf(mb, sc[Sn + s]); }
        float sa = 0.f, sb = 0.f;
        for (int s = 0; s < Sn; ++s) {
            float ea = expf(sc[s] - ma), eb = expf(sc[Sn + s] - mb);
            sc[s] = ea; sc[Sn + s] = eb; sa += ea; sb += eb;
        }
        float gs = 0.f;
        for (int s = 0; s < Sn; ++s) { float g = (sc[s] / sa) * (sc[Sn + s] / sb); g_sh[s] = g; gs += g; }
        float inv = 1.f / (gs + 1e-9f);
        float best = -1.f; int bi = 0;
        for (int s = 0; s < Sn; ++s) {
            float g = g_sh[s] * inv; g_sh[s] = g;
            if (g > best) { best = g; bi = s; }
        }
        smax_sh = bi;
    }
    __syncthreads();

    for (int s = tid; s < Sn; s += 256) gattn[(size_t)bt * Sn + s] = g_sh[s];
    const int word = value[b * Sn + smax_sh];
    for (int e = tid; e < TEn; e += 256)
        attn_pred[(size_t)bt * TEn + e] = target_emb[(size_t)word * TEn + e];

    for (int u = tid; u < Hn; u += 256) {
        float acc = 0.f;
        for (int s = 0; s < Sn; ++s)
            acc = fmaf(g_sh[s], enc_out[((size_t)b * Sn + s) * Hn + u], acc);
        ctx_sh[u] = acc;
    }
    __syncthreads();

    for (int j = tid; j < Hn; j += 256) {
        float acc = 0.f;
        for (int k = 0; k < Hn; ++k) acc = fmaf(h_sh[k], Wo[(size_t)k * Hn + j], acc);
        for (int k = 0; k < Hn; ++k) acc = fmaf(ctx_sh[k], Wo[(size_t)(Hn + k) * Hn + j], acc);
        outs[(size_t)bt * Hn + j] = tanhf(acc);
    }

    float part = 0.f;
    for (int k = tid; k < Hn; k += 256) part = fmaf(h_sh[k], Wl[k], part);
    for (int k = tid; k < Hn; k += 256) part = fmaf(ctx_sh[k], Wl[Hn + k], part);
    const float* xr = x_seq + (size_t)bt * SEn;
    for (int k = tid; k < SEn; k += 256) part = fmaf(xr[k], Wl[2 * Hn + k], part);
    red[tid] = part;
    __syncthreads();
    for (int s2 = 128; s2; s2 >>= 1) {
        if (tid < s2) red[tid] += red[tid + s2];
        __syncthreads();
    }
    if (tid == 0) lamv[bt] = 1.f / (1.f + expf(-(red[0] + bl[0])));
}

// ---------------------------------------------------------------------------
// p_lex (unchanged)
// ---------------------------------------------------------------------------
__global__ __launch_bounds__(256) void p_lex_kernel(
    const float* __restrict__ gattn, const float* __restrict__ align_prob,
    float* __restrict__ p_lex)
{
    const int b = blockIdx.z, th = blockIdx.y, vc = blockIdx.x;
    const int tid = threadIdx.x;
    __shared__ float gT[Sn][17];
    for (int i = tid; i < Sn * 16; i += 256) {
        int s = i >> 4, tt = i & 15;
        gT[s][tt] = gattn[((size_t)(b * Tn + th * 16 + tt)) * Sn + s];
    }
    __syncthreads();
    const int v0 = vc * 1024 + tid * 4;
    if (v0 >= Vn) return;
    float acc[16][4] = {};
    for (int s = 0; s < Sn; ++s) {
        const float4 a = *(const float4*)(align_prob + ((size_t)b * Sn + s) * Vn + v0);
        #pragma unroll
        for (int tt = 0; tt < 16; ++tt) {
            float g = gT[s][tt];
            acc[tt][0] = fmaf(g, a.x, acc[tt][0]);
            acc[tt][1] = fmaf(g, a.y, acc[tt][1]);
            acc[tt][2] = fmaf(g, a.z, acc[tt][2]);
            acc[tt][3] = fmaf(g, a.w, acc[tt][3]);
        }
    }
    #pragma unroll
    for (int tt = 0; tt < 16; ++tt) {
        float4 o;
        o.x = acc[tt][0]; o.y = acc[tt][1]; o.z = acc[tt][2]; o.w = acc[tt][3];
        *(float4*)(p_lex + ((size_t)(b * Tn + th * 16 + tt)) * Vn + v0) = o;
    }
}

// ---------------------------------------------------------------------------
// Row reductions (unchanged)
// ---------------------------------------------------------------------------
__global__ __launch_bounds__(256) void reduce1_kernel(
    const float* __restrict__ z, float* __restrict__ lse1)
{
    const int r = blockIdx.x, tid = threadIdx.x;
    const float* row = z + (size_t)r * Vn;
    __shared__ float red[256];
    float m = -1e30f;
    for (int v = tid; v < Vn; v += 256) m = fmaxf(m, row[v]);
    red[tid] = m; __syncthreads();
    for (int s = 128; s; s >>= 1) { if (tid < s) red[tid] = fmaxf(red[tid], red[tid + s]); __syncthreads(); }
    m = red[0]; __syncthreads();
    float sum = 0.f;
    for (int v = tid; v < Vn; v += 256) sum += expf(row[v] - m);
    red[tid] = sum; __syncthreads();
    for (int s = 128; s; s >>= 1) { if (tid < s) red[tid] += red[tid + s]; __syncthreads(); }
    if (tid == 0) lse1[r] = m + logf(red[0]);
}

__global__ __launch_bounds__(256) void combine_kernel(
    float* __restrict__ q, const float* __restrict__ p_lex,
    const float* __restrict__ lamv, const float* __restrict__ lse1,
    float* __restrict__ lse2, int* __restrict__ amax)
{
    const int r = blockIdx.x, tid = threadIdx.x;
    const float l = lamv[r], ls1 = lse1[r];
    float* row = q + (size_t)r * Vn;
    const float* pl = p_lex + (size_t)r * Vn;
    __shared__ float rm[256];
    __shared__ int ri[256];
    float m = -1e30f; int mi = 0;
    for (int v = tid; v < Vn; v += 256) {
        float qq = l * pl[v] + (1.f - l) * (row[v] - ls1);
        row[v] = qq;
        if (qq > m) { m = qq; mi = v; }
    }
    rm[tid] = m; ri[tid] = mi; __syncthreads();
    for (int s = 128; s; s >>= 1) {
        if (tid < s) {
            if (rm[tid + s] > rm[tid] || (rm[tid + s] == rm[tid] && ri[tid + s] < ri[tid])) {
                rm[tid] = rm[tid + s]; ri[tid] = ri[tid + s];
            }
        }
        __syncthreads();
    }
    m = rm[0];
    const int best = ri[0];
    __syncthreads();
    float sum = 0.f;
    for (int v = tid; v < Vn; v += 256) sum += expf(row[v] - m);
    rm[tid] = sum; __syncthreads();
    for (int s = 128; s; s >>= 1) { if (tid < s) rm[tid] += rm[tid + s]; __syncthreads(); }
    if (tid == 0) { lse2[r] = m + logf(rm[0]); amax[r] = best; }
}

__global__ __launch_bounds__(256) void finalize_kernel(
    float* __restrict__ pbias, const float* __restrict__ lse2,
    const int* __restrict__ amax, const float* __restrict__ target_emb,
    float* __restrict__ dec_pred)
{
    const int r = blockIdx.x, tid = threadIdx.x;
    const float ls = lse2[r];
    float* row = pbias + (size_t)r * Vn;
    for (int v = tid; v < Vn; v += 256) row[v] -= ls;
    const int wd = amax[r];
    for (int e = tid; e < TEn; e += 256)
        dec_pred[(size_t)r * TEn + e] = target_emb[(size_t)wd * TEn + e];
}

// ---------------------------------------------------------------------------
extern "C" void kernel_launch(void* const* d_in, const int* in_sizes, int n_in,
                              void* d_out, int out_size, void* d_ws, size_t ws_size,
                              hipStream_t stream)
{
    const int*   sent       = (const int*)d_in[0];
    const int*   value      = (const int*)d_in[1];
    const int*   field      = (const int*)d_in[2];
    const int*   ppos       = (const int*)d_in[3];
    const int*   pneg       = (const int*)d_in[4];
    const float* align_prob = (const float*)d_in[7];
    const float* sent_emb   = (const float*)d_in[8];
    const float* field_emb  = (const float*)d_in[9];
    const float* ppos_emb   = (const float*)d_in[10];
    const float* pneg_emb   = (const float*)d_in[11];
    const float* target_emb = (const float*)d_in[12];
    const float* Wi_f = (const float*)d_in[13];
    const float* Wh_f = (const float*)d_in[14];
    const float* b_f  = (const float*)d_in[15];
    const float* Wi_b = (const float*)d_in[16];
    const float* Wh_b = (const float*)d_in[17];
    const float* b_b  = (const float*)d_in[18];
    const float* Wi_d = (const float*)d_in[19];
    const float* Wh_d = (const float*)d_in[20];
    const float* b_d  = (const float*)d_in[21];
    const float* Wa   = (const float*)d_in[22];
    const float* Wf   = (const float*)d_in[23];
    const float* Wo   = (const float*)d_in[24];
    const float* Wl   = (const float*)d_in[25];
    const float* bl   = (const float*)d_in[26];
    const float* Wout = (const float*)d_in[27];
    const float* bout = (const float*)d_in[28];

    // Workspace layout (floats), same footprint as round 0 (~148.5 MB).
    float* w = (float*)d_ws;
    float* enc_in   = w; w += (size_t)Bn * Sn * EINn;   // 1,472,000
    float* x_seq    = w; w += (size_t)Bn * Tn * SEn;    //   409,600
    float* Xf       = w; w += (size_t)Bn * Sn * 1024;   // 3,276,800
    float* Xb       = w; w += (size_t)Bn * Sn * 1024;   // 3,276,800
    float* Xd       = w; w += (size_t)Bn * Tn * 2048;   // 2,097,152
    float* enc_out  = w; w += (size_t)Bn * Sn * Hn;     // 1,638,400
    float* enc_proj = w; w += (size_t)Bn * Sn * Hn;     // 1,638,400
    float* z_proj   = w; w += (size_t)Bn * Sn * Hn;     // 1,638,400
    float* h0       = w; w += (size_t)Bn * Hn;          //    16,384
    float* c0       = w; w += (size_t)Bn * Hn;          //    16,384
    float* h_all    = w; w += (size_t)Bn * Tn * Hn;     //   524,288
    float* outs     = w; w += (size_t)Bn * Tn * Hn;     //   524,288
    float* gattn    = w; w += (size_t)Bn * Tn * Sn;     //   102,400
    float* lamv     = w; w += (size_t)Bn * Tn;          //     1,024
    float* p_lex    = w; w += (size_t)Bn * Tn * Vn;     // 20,480,000
    float* lse1     = w; w += (size_t)Bn * Tn;
    float* lse2     = w; w += (size_t)Bn * Tn;
    int*   amax     = (int*)w;

    // Transposed LSTM weights + decoder h-exchange buffer + barrier counter,
    // aliased into the p_lex region (all dead before p_lex_kernel writes).
    float* Whf_t = p_lex;                       // 262,144 floats
    float* Whb_t = p_lex + 262144;              // 262,144
    float* Whd_t = p_lex + 524288;              // 1,048,576
    float* hbuf  = p_lex + 2000000;             //    16,384
    int*   bar   = (int*)(p_lex + 2100000);     // 1 int

    float* outp      = (float*)d_out;
    float* pbias     = outp;                       // [B,T,V]
    float* hT        = outp + (size_t)20480000;    // [B,H]
    float* cT        = hT + Bn * Hn;               // [B,H]
    float* attn_pred = cT + Bn * Hn;               // [B,T,300]
    float* dec_pred  = attn_pred + (size_t)Bn * Tn * TEn;

    // 1. embeddings + weight transposes
    embed_kernel<<<7350, 256, 0, stream>>>(value, field, ppos, pneg, sent,
        sent_emb, field_emb, ppos_emb, pneg_emb, enc_in, x_seq);
    transpose_wh_kernel<<<1280, 256, 0, stream>>>(Wh_f, Wh_b, Wh_d, Whf_t, Whb_t, Whd_t);

    // 2. input-side GEMMs
    dim3 gXf(8, 25);
    gemm128_kernel<<<gXf, 256, 0, stream>>>(enc_in, Wi_f, b_f, Xf, 3200, 1024, 460, 460, 1024, 1024);
    gemm128_kernel<<<gXf, 256, 0, stream>>>(enc_in, Wi_b, b_b, Xb, 3200, 1024, 460, 460, 1024, 1024);
    dim3 gXd(16, 8);
    gemm128_kernel<<<gXd, 256, 0, stream>>>(x_seq, Wi_d, b_d, Xd, 1024, 2048, 400, 400, 2048, 2048);

    // 3. encoder bidirectional LSTM
    enc_lstm2_kernel<<<64, 256, 0, stream>>>(Xf, Xb, (const float4*)Whf_t,
        (const float4*)Whb_t, enc_out, h0, c0);

    // 4. attention key projections
    dim3 gPr(4, 25);
    gemm128_kernel<<<gPr, 256, 0, stream>>>(enc_out, Wa, nullptr, enc_proj, 3200, 512, 512, 512, 512, 512);
    gemm128_kernel<<<gPr, 256, 0, stream>>>(enc_in + 400, Wf, nullptr, z_proj, 3200, 512, 60, 460, 512, 512);

    // 5. decoder LSTM — cooperative launch with grid barrier per step
    hipMemsetAsync(bar, 0, 64, stream);
    {
        void* args[] = { (void*)&Xd, (void*)&Whd_t, (void*)&h0, (void*)&c0,
                         (void*)&h_all, (void*)&hT, (void*)&cT,
                         (void*)&hbuf, (void*)&bar };
        hipLaunchCooperativeKernel((const void*)dec_lstm2_kernel,
                                   dim3(64), dim3(256), args, 0, stream);
    }

    // 6. per-(b,t) attention/ctx/out/lam
    dec_post_kernel<<<1024, 256, 0, stream>>>(h_all, enc_proj, z_proj, enc_out, x_seq,
        Wo, Wl, bl, value, target_emb, outs, gattn, lamv, attn_pred);

    // 7. zmod = outs @ Wout + bout
    dim3 gBig(157, 8);
    gemm128_kernel<<<gBig, 256, 0, stream>>>(outs, Wout, bout, pbias, 1024, 20000, 512, 512, 20000, 20000);

    // 8. p_lex = attn @ align_prob
    dim3 gPl(20, 2, 32);
    p_lex_kernel<<<gPl, 256, 0, stream>>>(gattn, align_prob, p_lex);

    // 9-11. double log_softmax + argmax + gathers
    reduce1_kernel<<<1024, 256, 0, stream>>>(pbias, lse1);
    combine_kernel<<<1024, 256, 0, stream>>>(pbias, p_lex, lamv, lse1, lse2, amax);
    finalize_kernel<<<1024, 256, 0, stream>>>(pbias, lse2, amax, target_emb, dec_pred);

    (void)in_sizes; (void)n_in; (void)out_size; (void)ws_size;
}